// Round 5
// baseline (331.390 us; speedup 1.0000x reference)
//
#include <hip/hip_runtime.h>
#include <hip/hip_bf16.h>
#include <math.h>

// Problem constants: B=32, O=4096, F=256, H=8, HID=128
#define MB_ 131072
#define F_  256
#define HID_ 128
#define H_  8
#define O_  4096
#define B_  32

typedef __attribute__((ext_vector_type(8))) short short8;
typedef __attribute__((ext_vector_type(4))) float f32x4;

static __device__ __forceinline__ unsigned short f2bf(float f) {
    unsigned int u = __float_as_uint(f);
    unsigned int r = (u + 0x7fffu + ((u >> 16) & 1u)) >> 16;  // RNE
    return (unsigned short)r;
}
static __device__ __forceinline__ float bf2f(unsigned short u) {
    return __uint_as_float(((unsigned int)u) << 16);
}
static __device__ __forceinline__ unsigned int pk2bf(float a, float b) {
    float2 f2; f2.x = a; f2.y = b;
    __hip_bfloat162 h = __float22bfloat162_rn(f2);
    union { __hip_bfloat162 h2; unsigned int u; } cv;
    cv.h2 = h;
    return cv.u;
}

// ---------------- Prep: weights -> fragment-major bf16 ----------------------
// Frag-major: W_f[ (chunk*128 + n)*8 + j ] = W[k = chunk*8 + j][n]
// so a B-fragment load (lane lm, quad) is 16 B contiguous, lanes consecutive.
__global__ __launch_bounds__(256) void k_prep(
    const float* __restrict__ W_in, const float* __restrict__ W_blk,
    unsigned short* __restrict__ Win_f, unsigned short* __restrict__ Wblk_f)
{
    const int idx = blockIdx.x * 256 + threadIdx.x;
    if (idx < 32768) {                        // Win_f: chunks 0..31 (K=256)
        const int j = idx & 7, n = (idx >> 3) & 127, c = idx >> 10;
        Win_f[idx] = f2bf(W_in[(size_t)(c * 8 + j) * HID_ + n]);
    } else if (idx < 49152) {                 // Wblk_f: chunks 0..15 (K=128)
        const int i2 = idx - 32768;
        const int j = i2 & 7, n = (i2 >> 3) & 127, c = i2 >> 10;
        Wblk_f[i2] = f2bf(W_blk[(size_t)(c * 8 + j) * HID_ + n]);
    }
}

// ---------------- Phase A: h = relu(x@W_in+b_in); BN partials of z ----------
// grid 1024, block 256 (4 waves), 128 rows/block, 3 blocks/CU.
// x staged via double-buffered fragment-major bf16 LDS (coalesced loads);
// weights direct from global in fragment-major layout (coalesced, L2-hot).
__global__ __launch_bounds__(256, 3) void k_phaseA(
    const float* __restrict__ x, const unsigned short* __restrict__ Win_f,
    const unsigned short* __restrict__ Wblk_f,
    const float* __restrict__ b_in, const float* __restrict__ b_blk,
    unsigned short* __restrict__ h_out, float* __restrict__ mask_out,
    float* __restrict__ sumP, float* __restrict__ sumsqP)
{
    __shared__ __align__(16) unsigned short a_s[2][4 * 132 * 8]; // 2x8448 B
    __shared__ __align__(16) unsigned short hb_s[128 * 136];     // 34816 B
    __shared__ float csum_s[128], csumsq_s[128];

    const int tid = threadIdx.x;
    const int R0 = blockIdx.x * 128;
    const int wave = tid >> 6;
    const int wrow = wave >> 1, wcol = wave & 1;
    const int lane = tid & 63;
    const int lm = lane & 15, quad = lane >> 4;
    // stager: thread covers rows (tid>>3)+32p, k-quad (tid&7) of each 32-k tile
    const int srow = tid >> 3;
    const int sk = tid & 7;
    const int sq = sk >> 1, sh = sk & 1;

    if (tid < 128) { csum_s[tid] = 0.f; csumsq_s[tid] = 0.f; }

    f32x4 acc[4][4];
#pragma unroll
    for (int i = 0; i < 4; i++)
#pragma unroll
        for (int j = 0; j < 4; j++) acc[i][j] = (f32x4){0.f, 0.f, 0.f, 0.f};
    float ms[4] = {0.f, 0.f, 0.f, 0.f};

    const float* xrow = x + (size_t)(R0 + srow) * F_ + sk * 4;

    // stage kt=0
#pragma unroll
    for (int p = 0; p < 4; p++) {
        const float4 v = *(const float4*)(xrow + (size_t)(32 * p) * F_);
        ms[p] += v.x * v.x + v.y * v.y + v.z * v.z + v.w * v.w;
        uint2 w; w.x = pk2bf(v.x, v.y); w.y = pk2bf(v.z, v.w);
        *(uint2*)(&a_s[0][(sq * 132 + srow + 32 * p) * 8 + sh * 4]) = w;
    }
    __syncthreads();

    // ---- GEMM1: K = 256 in 8 kt, double-buffered, 1 barrier/kt ----
    for (int kt = 0; kt < 8; kt++) {
        const int cur = kt & 1;
        float4 nv[4];
        if (kt < 7) {
#pragma unroll
            for (int p = 0; p < 4; p++)
                nv[p] = *(const float4*)(xrow + (kt + 1) * 32 + (size_t)(32 * p) * F_);
        }
        short8 bfr[4], af[4];
        const unsigned short* wf = Win_f + ((size_t)(kt * 4 + quad) * 128 + wcol * 64 + lm) * 8;
#pragma unroll
        for (int ni = 0; ni < 4; ni++)
            bfr[ni] = *(const short8*)(wf + ni * 16 * 8);
#pragma unroll
        for (int mi = 0; mi < 4; mi++)
            af[mi] = *(const short8*)(&a_s[cur][(quad * 132 + wrow * 64 + mi * 16 + lm) * 8]);
#pragma unroll
        for (int mi = 0; mi < 4; mi++)
#pragma unroll
            for (int ni = 0; ni < 4; ni++)
                acc[mi][ni] = __builtin_amdgcn_mfma_f32_16x16x32_bf16(af[mi], bfr[ni], acc[mi][ni], 0, 0, 0);
        if (kt < 7) {
#pragma unroll
            for (int p = 0; p < 4; p++) {
                ms[p] += nv[p].x * nv[p].x + nv[p].y * nv[p].y
                       + nv[p].z * nv[p].z + nv[p].w * nv[p].w;
                uint2 w; w.x = pk2bf(nv[p].x, nv[p].y); w.y = pk2bf(nv[p].z, nv[p].w);
                *(uint2*)(&a_s[1 - cur][(sq * 132 + srow + 32 * p) * 8 + sh * 4]) = w;
            }
        }
        __syncthreads();
    }

    // ---- row mask: 8 stager threads per row cover the full K ----
#pragma unroll
    for (int p = 0; p < 4; p++) {
        float s = ms[p];
        s += __shfl_down(s, 4, 8);
        s += __shfl_down(s, 2, 8);
        s += __shfl_down(s, 1, 8);
        if (sk == 0) mask_out[R0 + srow + 32 * p] = (s != 0.f) ? 1.f : 0.f;
    }

    // ---- epilogue 1: bias + relu -> hb_s ----
    {
        float bcol[4];
#pragma unroll
        for (int ni = 0; ni < 4; ni++) bcol[ni] = b_in[wcol * 64 + ni * 16 + lm];
#pragma unroll
        for (int mi = 0; mi < 4; mi++)
#pragma unroll
            for (int r = 0; r < 4; r++) {
                const int row = wrow * 64 + mi * 16 + quad * 4 + r;
#pragma unroll
                for (int ni = 0; ni < 4; ni++) {
                    const int col = wcol * 64 + ni * 16 + lm;
                    hb_s[row * 136 + col] = f2bf(fmaxf(acc[mi][ni][r] + bcol[ni], 0.f));
                }
            }
    }
    __syncthreads();

    // ---- coalesced h store from LDS ----
    {
        const int row = tid >> 1, half = tid & 1;
#pragma unroll
        for (int c8 = 0; c8 < 8; c8++) {
            const short8 v = *(const short8*)(&hb_s[row * 136 + half * 64 + c8 * 8]);
            *(short8*)(h_out + (size_t)(R0 + row) * HID_ + half * 64 + c8 * 8) = v;
        }
    }

    // ---- GEMM2: z = h @ W_blk (A from hb_s, B frag-major global) ----
#pragma unroll
    for (int i = 0; i < 4; i++)
#pragma unroll
        for (int j = 0; j < 4; j++) acc[i][j] = (f32x4){0.f, 0.f, 0.f, 0.f};
#pragma unroll
    for (int kt = 0; kt < 4; kt++) {
        short8 af[4], bfr[4];
        const unsigned short* wf2 = Wblk_f + ((size_t)(kt * 4 + quad) * 128 + wcol * 64 + lm) * 8;
#pragma unroll
        for (int ni = 0; ni < 4; ni++)
            bfr[ni] = *(const short8*)(wf2 + ni * 16 * 8);
#pragma unroll
        for (int mi = 0; mi < 4; mi++)
            af[mi] = *(const short8*)(&hb_s[(wrow * 64 + mi * 16 + lm) * 136 + kt * 32 + quad * 8]);
#pragma unroll
        for (int mi = 0; mi < 4; mi++)
#pragma unroll
            for (int ni = 0; ni < 4; ni++)
                acc[mi][ni] = __builtin_amdgcn_mfma_f32_16x16x32_bf16(af[mi], bfr[ni], acc[mi][ni], 0, 0, 0);
    }

    // ---- epilogue 2: BN partial sums (z never stored) ----
    {
        float bcol[4];
#pragma unroll
        for (int ni = 0; ni < 4; ni++) bcol[ni] = b_blk[wcol * 64 + ni * 16 + lm];
        float s_c[4] = {0.f, 0.f, 0.f, 0.f}, ss_c[4] = {0.f, 0.f, 0.f, 0.f};
#pragma unroll
        for (int mi = 0; mi < 4; mi++)
#pragma unroll
            for (int r = 0; r < 4; r++)
#pragma unroll
                for (int ni = 0; ni < 4; ni++) {
                    const float zv = acc[mi][ni][r] + bcol[ni];
                    s_c[ni] += zv;
                    ss_c[ni] += zv * zv;
                }
#pragma unroll
        for (int ni = 0; ni < 4; ni++) {
            float s = s_c[ni], ss = ss_c[ni];
            s  += __shfl_xor(s, 16);  s  += __shfl_xor(s, 32);
            ss += __shfl_xor(ss, 16); ss += __shfl_xor(ss, 32);
            if (quad == 0) {
                atomicAdd(&csum_s[wcol * 64 + ni * 16 + lm], s);
                atomicAdd(&csumsq_s[wcol * 64 + ni * 16 + lm], ss);
            }
        }
    }
    __syncthreads();
    if (tid < 128) {
        sumP[(size_t)blockIdx.x * 128 + tid] = csum_s[tid];
        sumsqP[(size_t)blockIdx.x * 128 + tid] = csumsq_s[tid];
    }
}

// ---------------- BN finalize ----------------------------------------------
__global__ __launch_bounds__(256) void k_bnfin(
    const float* __restrict__ sumP, const float* __restrict__ sumsqP,
    const float* __restrict__ gamma, const float* __restrict__ beta,
    float* __restrict__ scale, float* __restrict__ shift)
{
    const int c = blockIdx.x;
    const int tid = threadIdx.x;
    float s = 0.f, ss = 0.f;
    for (int i = tid; i < 1024; i += 256) {
        s  += sumP[(size_t)i * 128 + c];
        ss += sumsqP[(size_t)i * 128 + c];
    }
#pragma unroll
    for (int off = 32; off; off >>= 1) {
        s  += __shfl_xor(s, off, 64);
        ss += __shfl_xor(ss, off, 64);
    }
    __shared__ float rs[4], rss[4];
    const int wid = tid >> 6, lane = tid & 63;
    if (lane == 0) { rs[wid] = s; rss[wid] = ss; }
    __syncthreads();
    if (tid == 0) {
        const float S  = rs[0] + rs[1] + rs[2] + rs[3];
        const float SS = rss[0] + rss[1] + rss[2] + rss[3];
        const float inv_m = 1.0f / (float)MB_;
        const float mu = S * inv_m;
        const float var = SS * inv_m - mu * mu;
        const float sc = gamma[c] * rsqrtf(var + 1e-5f);
        scale[c] = sc;
        shift[c] = beta[c] - mu * sc;
    }
}

// ---------------- Phase C: recompute z, BN, residual, logits, t -------------
// grid 1024 (128 rows), block 256, 4 blocks/CU. t in (b,h,o) layout.
__global__ __launch_bounds__(256, 4) void k_phaseC(
    const unsigned short* __restrict__ h_in, const unsigned short* __restrict__ Wblk_f,
    const float* __restrict__ b_blk,
    const float* __restrict__ scale, const float* __restrict__ shift,
    const float* __restrict__ W_fc, const float* __restrict__ b_fc,
    const float* __restrict__ mask, const float* __restrict__ gumbel,
    float* __restrict__ t_bho)
{
    __shared__ __align__(16) unsigned short hb_s[128 * 136];
    __shared__ float wfc_s[128 * 8];
    __shared__ float sc_s[128], sh_s[128];

    const int tid = threadIdx.x;
    const int R0 = blockIdx.x * 128;
    const int wave = tid >> 6;
    const int wrow = wave >> 1, wcol = wave & 1;
    const int lane = tid & 63;
    const int lm = lane & 15, quad = lane >> 4;

    for (int i = tid; i < 1024; i += 256) wfc_s[i] = W_fc[i];
    if (tid < 128) { sc_s[tid] = scale[tid]; sh_s[tid] = shift[tid]; }
    // stage h tile (coalesced)
    {
        const int row = tid >> 1, half = tid & 1;
#pragma unroll
        for (int c8 = 0; c8 < 8; c8++) {
            const short8 v = *(const short8*)(h_in + (size_t)(R0 + row) * HID_ + half * 64 + c8 * 8);
            *(short8*)(&hb_s[row * 136 + half * 64 + c8 * 8]) = v;
        }
    }
    __syncthreads();

    f32x4 acc[4][4];
#pragma unroll
    for (int i = 0; i < 4; i++)
#pragma unroll
        for (int j = 0; j < 4; j++) acc[i][j] = (f32x4){0.f, 0.f, 0.f, 0.f};
#pragma unroll
    for (int kt = 0; kt < 4; kt++) {
        short8 af[4], bfr[4];
        const unsigned short* wf2 = Wblk_f + ((size_t)(kt * 4 + quad) * 128 + wcol * 64 + lm) * 8;
#pragma unroll
        for (int ni = 0; ni < 4; ni++)
            bfr[ni] = *(const short8*)(wf2 + ni * 16 * 8);
#pragma unroll
        for (int mi = 0; mi < 4; mi++)
            af[mi] = *(const short8*)(&hb_s[(wrow * 64 + mi * 16 + lm) * 136 + kt * 32 + quad * 8]);
#pragma unroll
        for (int mi = 0; mi < 4; mi++)
#pragma unroll
            for (int ni = 0; ni < 4; ni++)
                acc[mi][ni] = __builtin_amdgcn_mfma_f32_16x16x32_bf16(af[mi], bfr[ni], acc[mi][ni], 0, 0, 0);
    }

    // epilogue: hb = relu(z*sc+sh) + h, in place
    {
        float bcol[4];
#pragma unroll
        for (int ni = 0; ni < 4; ni++) bcol[ni] = b_blk[wcol * 64 + ni * 16 + lm];
#pragma unroll
        for (int mi = 0; mi < 4; mi++)
#pragma unroll
            for (int r = 0; r < 4; r++) {
                const int row = wrow * 64 + mi * 16 + quad * 4 + r;
#pragma unroll
                for (int ni = 0; ni < 4; ni++) {
                    const int col = wcol * 64 + ni * 16 + lm;
                    const float zv = acc[mi][ni][r] + bcol[ni];
                    const float hv = bf2f(hb_s[row * 136 + col]);
                    const float hb = fmaxf(zv * sc_s[col] + sh_s[col], 0.f) + hv;
                    hb_s[row * 136 + col] = f2bf(hb);
                }
            }
    }
    __syncthreads();

    // logits + gumbel: thread pair (row = tid>>1) splits K=128 in half
    {
        const int row = tid >> 1, half = tid & 1;
        const int grow = R0 + row;
        float a8[8];
#pragma unroll
        for (int j = 0; j < 8; j++) a8[j] = 0.f;
#pragma unroll 2
        for (int k8 = 0; k8 < 8; k8++) {
            const short8 hv8 = *(const short8*)(&hb_s[row * 136 + half * 64 + k8 * 8]);
#pragma unroll
            for (int e = 0; e < 8; e++) {
                const float hv = bf2f((unsigned short)hv8[e]);
                const int k = half * 64 + k8 * 8 + e;
#pragma unroll
                for (int j = 0; j < 8; j++) a8[j] += hv * wfc_s[k * 8 + j];
            }
        }
#pragma unroll
        for (int j = 0; j < 8; j++) a8[j] += __shfl_xor(a8[j], 1);
        const float mk = mask[grow];
        const int b = grow >> 12, o = grow & 4095;
#pragma unroll
        for (int jj = 0; jj < 4; jj++) {
            const int j = half * 4 + jj;
            const float t = (a8[j] + b_fc[j]) * mk + gumbel[(size_t)grow * 8 + j];
            t_bho[((size_t)(b * 8 + j)) * O_ + o] = t;
        }
    }
}

// ---------------- softmax over O per (b,h), coalesced -----------------------
__global__ __launch_bounds__(256) void k_softmax(
    const float* __restrict__ t_in, float* __restrict__ w_out)
{
    const int bh = blockIdx.x;
    const int tid = threadIdx.x;
    const float* tp = t_in + (size_t)bh * O_;
    float4 v[4];
    float mx = -3.4e38f;
#pragma unroll
    for (int it = 0; it < 4; it++) {
        v[it] = *(const float4*)(tp + it * 1024 + tid * 4);
        mx = fmaxf(mx, fmaxf(fmaxf(v[it].x, v[it].y), fmaxf(v[it].z, v[it].w)));
    }
#pragma unroll
    for (int off = 32; off; off >>= 1) mx = fmaxf(mx, __shfl_xor(mx, off, 64));
    __shared__ float rm[4], rsum[4];
    const int wid = tid >> 6, lane = tid & 63;
    if (lane == 0) rm[wid] = mx;
    __syncthreads();
    mx = fmaxf(fmaxf(rm[0], rm[1]), fmaxf(rm[2], rm[3]));
    float sum = 0.f;
#pragma unroll
    for (int it = 0; it < 4; it++) {
        v[it].x = __expf(v[it].x - mx); v[it].y = __expf(v[it].y - mx);
        v[it].z = __expf(v[it].z - mx); v[it].w = __expf(v[it].w - mx);
        sum += v[it].x + v[it].y + v[it].z + v[it].w;
    }
#pragma unroll
    for (int off = 32; off; off >>= 1) sum += __shfl_xor(sum, off, 64);
    if (lane == 0) rsum[wid] = sum;
    __syncthreads();
    sum = rsum[0] + rsum[1] + rsum[2] + rsum[3];
    const float inv = 1.f / sum;
    float* wp = w_out + (size_t)bh * O_;
#pragma unroll
    for (int it = 0; it < 4; it++) {
        float4 o;
        o.x = v[it].x * inv; o.y = v[it].y * inv; o.z = v[it].z * inv; o.w = v[it].w * inv;
        *(float4*)(wp + it * 1024 + tid * 4) = o;
    }
}

// ---------------- pooled partials -------------------------------------------
__global__ __launch_bounds__(256) void k_pool(
    const float* __restrict__ x, const float* __restrict__ w_in,
    float* __restrict__ pp)
{
    __shared__ float ws_s[8][128];
    const int tid = threadIdx.x;
    const int oc = blockIdx.x;
    const int b = blockIdx.y;
    const int wave = tid >> 6, lane = tid & 63;
    const int f = wave * 64 + lane;
    for (int i = tid; i < 1024; i += 256) {
        const int hh = i >> 7, oi = i & 127;
        ws_s[hh][oi] = w_in[((size_t)(b * 8 + hh)) * O_ + oc * 128 + oi];
    }
    __syncthreads();
    float acc[8];
#pragma unroll
    for (int hh = 0; hh < 8; hh++) acc[hh] = 0.f;
    const float* xp = x + ((size_t)(b * O_ + oc * 128)) * F_ + f;
#pragma unroll 1
    for (int oi = 0; oi < 128; oi += 4) {
        float xv[4];
#pragma unroll
        for (int u = 0; u < 4; u++) xv[u] = xp[(size_t)(oi + u) * F_];
#pragma unroll
        for (int u = 0; u < 4; u++)
#pragma unroll
            for (int hh = 0; hh < 8; hh++) acc[hh] += ws_s[hh][oi + u] * xv[u];
    }
    float* outp = pp + ((size_t)(oc * 32 + b)) * 2048;
#pragma unroll
    for (int hh = 0; hh < 8; hh++) outp[hh * 256 + f] = acc[hh];
}

// ---------------- reduce pooled partials ------------------------------------
__global__ __launch_bounds__(256) void k_reduce_pool(
    const float* __restrict__ pp, float* __restrict__ out)
{
    const size_t i = (size_t)blockIdx.x * 256 + threadIdx.x;
    float s = 0.f;
#pragma unroll
    for (int oc = 0; oc < 32; oc++) s += pp[(size_t)oc * 65536 + i];
    out[i] = s;
}

extern "C" void kernel_launch(void* const* d_in, const int* in_sizes, int n_in,
                              void* d_out, int out_size, void* d_ws, size_t ws_size,
                              hipStream_t stream)
{
    const float* x      = (const float*)d_in[0];
    const float* gumbel = (const float*)d_in[1];
    const float* W_in   = (const float*)d_in[2];
    const float* b_in   = (const float*)d_in[3];
    const float* W_blk  = (const float*)d_in[4];
    const float* b_blk  = (const float*)d_in[5];
    const float* gamma  = (const float*)d_in[6];
    const float* beta   = (const float*)d_in[7];
    const float* W_fc   = (const float*)d_in[8];
    const float* b_fc   = (const float*)d_in[9];
    float* out = (float*)d_out;
    char* ws = (char*)d_ws;

    unsigned short* h_bf  = (unsigned short*)(ws + 0);             // 33554432
    float* mask   = (float*)(ws + 33554432);                        // 524288
    float* sumP   = (float*)(ws + 34078720);                        // 524288
    float* sumsqP = (float*)(ws + 34603008);                        // 524288
    float* scale  = (float*)(ws + 35127296);                        // 512
    float* shift  = (float*)(ws + 35127808);                        // 512
    float* t_buf  = (float*)(ws + 35128320);                        // 4194304
    float* w_buf  = (float*)(ws + 39322624);                        // 4194304
    float* pp     = (float*)(ws + 43516928);                        // 8388608
    unsigned short* Win_f  = (unsigned short*)(ws + 51905536);      // 65536
    unsigned short* Wblk_f = (unsigned short*)(ws + 51971072);      // 32768

    k_prep<<<192, 256, 0, stream>>>(W_in, W_blk, Win_f, Wblk_f);
    k_phaseA<<<1024, 256, 0, stream>>>(x, Win_f, Wblk_f, b_in, b_blk, h_bf, mask, sumP, sumsqP);
    k_bnfin<<<128, 256, 0, stream>>>(sumP, sumsqP, gamma, beta, scale, shift);
    k_phaseC<<<1024, 256, 0, stream>>>(h_bf, Wblk_f, b_blk, scale, shift, W_fc, b_fc, mask, gumbel, t_buf);
    k_softmax<<<256, 256, 0, stream>>>(t_buf, w_buf);
    k_pool<<<dim3(32, 32), 256, 0, stream>>>(x, w_buf, pp);
    k_reduce_pool<<<256, 256, 0, stream>>>(pp, out);
}

// Round 6
// 316.328 us; speedup vs baseline: 1.0476x; 1.0476x over previous
//
#include <hip/hip_runtime.h>
#include <hip/hip_bf16.h>
#include <math.h>

// Problem constants: B=32, O=4096, F=256, H=8, HID=128
#define MB_ 131072
#define F_  256
#define HID_ 128
#define H_  8
#define O_  4096
#define B_  32

typedef __attribute__((ext_vector_type(8))) short short8;
typedef __attribute__((ext_vector_type(4))) float f32x4;

static __device__ __forceinline__ unsigned short f2bf(float f) {
    unsigned int u = __float_as_uint(f);
    unsigned int r = (u + 0x7fffu + ((u >> 16) & 1u)) >> 16;  // RNE
    return (unsigned short)r;
}
static __device__ __forceinline__ float bf2f(unsigned short u) {
    return __uint_as_float(((unsigned int)u) << 16);
}
static __device__ __forceinline__ unsigned int pk2bf(float a, float b) {
    float2 f2; f2.x = a; f2.y = b;
    __hip_bfloat162 h = __float22bfloat162_rn(f2);
    union { __hip_bfloat162 h2; unsigned int u; } cv;
    cv.h2 = h;
    return cv.u;
}

// ---------------- Prep: weights -> fragment-major bf16 ----------------------
// W_f[(c*128 + n)*8 + j] = W[k = c*8 + j][n]; B-frag = 16 B contiguous/lane.
__global__ __launch_bounds__(256) void k_prep(
    const float* __restrict__ W_in, const float* __restrict__ W_blk,
    unsigned short* __restrict__ Win_f, unsigned short* __restrict__ Wblk_f)
{
    const int idx = blockIdx.x * 256 + threadIdx.x;
    if (idx < 32768) {                        // Win_f: c 0..31 (K=256)
        const int j = idx & 7, n = (idx >> 3) & 127, c = idx >> 10;
        Win_f[idx] = f2bf(W_in[(size_t)(c * 8 + j) * HID_ + n]);
    } else if (idx < 49152) {                 // Wblk_f: c 0..15 (K=128)
        const int i2 = idx - 32768;
        const int j = i2 & 7, n = (i2 >> 3) & 127, c = i2 >> 10;
        Wblk_f[i2] = f2bf(W_blk[(size_t)(c * 8 + j) * HID_ + n]);
    }
}

// ---------------- GEMM1: h = relu(x@W_in+b_in), frag-major h out, mask ------
// grid 1024, block 256 (4 waves). LDS = union(x-stage 8.4KB, h-tile 34.8KB)
// -> 4 blocks/CU. Weights direct from global (frag-major, L2-hot). No
// prefetch registers (round-5 spill lesson). h stored FRAGMENT-MAJOR:
// h_f[tile*16384 + (c*128 + row)*8 + j], col = c*8+j.
__global__ __launch_bounds__(256, 3) void k_gemm1(
    const float* __restrict__ x, const unsigned short* __restrict__ Win_f,
    const float* __restrict__ b_in,
    unsigned short* __restrict__ h_f, float* __restrict__ mask_out)
{
    __shared__ __align__(16) unsigned short smem[128 * 136];  // 34816 B
    unsigned short* a_s = smem;          // [4][132][8] = 4224 shorts (K loop)
    unsigned short* hb_s = smem;         // [128][136] row-major (epilogue)

    const int tid = threadIdx.x;
    const int R0 = blockIdx.x * 128;
    const int wave = tid >> 6;
    const int wrow = wave >> 1, wcol = wave & 1;
    const int lane = tid & 63;
    const int lm = lane & 15, quad = lane >> 4;
    const int srow = tid >> 3;           // stager row 0..31
    const int sk = tid & 7;              // stager k-quad
    const int sq = sk >> 1, sh = sk & 1;

    f32x4 acc[4][4];
#pragma unroll
    for (int i = 0; i < 4; i++)
#pragma unroll
        for (int j = 0; j < 4; j++) acc[i][j] = (f32x4){0.f, 0.f, 0.f, 0.f};
    float ms[4] = {0.f, 0.f, 0.f, 0.f};

    const float* xrow = x + (size_t)(R0 + srow) * F_ + sk * 4;

    for (int kt = 0; kt < 8; kt++) {
        // stage x tile (bf16, frag-major) — coalesced 128 B/row-group reads
#pragma unroll
        for (int p = 0; p < 4; p++) {
            const float4 v = *(const float4*)(xrow + kt * 32 + (size_t)(32 * p) * F_);
            ms[p] += v.x * v.x + v.y * v.y + v.z * v.z + v.w * v.w;
            uint2 w; w.x = pk2bf(v.x, v.y); w.y = pk2bf(v.z, v.w);
            *(uint2*)(&a_s[(sq * 132 + srow + 32 * p) * 8 + sh * 4]) = w;
        }
        __syncthreads();
        short8 af[4], bfr[4];
        const unsigned short* wf = Win_f + ((size_t)(kt * 4 + quad) * 128 + wcol * 64 + lm) * 8;
#pragma unroll
        for (int ni = 0; ni < 4; ni++)
            bfr[ni] = *(const short8*)(wf + ni * 16 * 8);
#pragma unroll
        for (int mi = 0; mi < 4; mi++)
            af[mi] = *(const short8*)(&a_s[(quad * 132 + wrow * 64 + mi * 16 + lm) * 8]);
#pragma unroll
        for (int mi = 0; mi < 4; mi++)
#pragma unroll
            for (int ni = 0; ni < 4; ni++)
                acc[mi][ni] = __builtin_amdgcn_mfma_f32_16x16x32_bf16(af[mi], bfr[ni], acc[mi][ni], 0, 0, 0);
        __syncthreads();
    }

    // row mask: 8 stager lanes per row cover full K
#pragma unroll
    for (int p = 0; p < 4; p++) {
        float s = ms[p];
        s += __shfl_down(s, 4, 8);
        s += __shfl_down(s, 2, 8);
        s += __shfl_down(s, 1, 8);
        if (sk == 0) mask_out[R0 + srow + 32 * p] = (s != 0.f) ? 1.f : 0.f;
    }

    // epilogue: bias + relu -> hb_s (row-major; safe, a_s dead after barrier)
    {
        float bcol[4];
#pragma unroll
        for (int ni = 0; ni < 4; ni++) bcol[ni] = b_in[wcol * 64 + ni * 16 + lm];
#pragma unroll
        for (int mi = 0; mi < 4; mi++)
#pragma unroll
            for (int r = 0; r < 4; r++) {
                const int row = wrow * 64 + mi * 16 + quad * 4 + r;
#pragma unroll
                for (int ni = 0; ni < 4; ni++) {
                    const int col = wcol * 64 + ni * 16 + lm;
                    hb_s[row * 136 + col] = f2bf(fmaxf(acc[mi][ni][r] + bcol[ni], 0.f));
                }
            }
    }
    __syncthreads();

    // frag-major h store: lane-contiguous 16 B -> 4 KB/instr
    unsigned short* hf = h_f + (size_t)blockIdx.x * 16384;
#pragma unroll
    for (int i = 0; i < 8; i++) {
        const int idx = i * 256 + tid;           // (c,row) chunk id
        const int c = idx >> 7, row = idx & 127;
        const short8 v = *(const short8*)(&hb_s[row * 136 + c * 8]);
        *(short8*)(hf + (size_t)idx * 8) = v;
    }
}

// ---------------- GEMM2 stats: BN column sums of z (z not stored) -----------
// grid 1024, block 256. A-frags direct from frag-major h (coalesced 256 B
// segments), B-frags direct from frag-major W_blk. No staging LDS, no
// K-loop barriers -> wave-limited occupancy.
__global__ __launch_bounds__(256, 4) void k_gemm2stats(
    const unsigned short* __restrict__ h_f, const unsigned short* __restrict__ Wblk_f,
    const float* __restrict__ b_blk,
    float* __restrict__ sumP, float* __restrict__ sumsqP)
{
    __shared__ float csum_s[128], csumsq_s[128];
    const int tid = threadIdx.x;
    const int wave = tid >> 6;
    const int wrow = wave >> 1, wcol = wave & 1;
    const int lane = tid & 63;
    const int lm = lane & 15, quad = lane >> 4;

    if (tid < 128) { csum_s[tid] = 0.f; csumsq_s[tid] = 0.f; }
    __syncthreads();

    const unsigned short* hf = h_f + (size_t)blockIdx.x * 16384;

    f32x4 acc[4][4];
#pragma unroll
    for (int i = 0; i < 4; i++)
#pragma unroll
        for (int j = 0; j < 4; j++) acc[i][j] = (f32x4){0.f, 0.f, 0.f, 0.f};
#pragma unroll
    for (int kt = 0; kt < 4; kt++) {
        short8 af[4], bfr[4];
        const unsigned short* wf2 = Wblk_f + ((size_t)(kt * 4 + quad) * 128 + wcol * 64 + lm) * 8;
#pragma unroll
        for (int ni = 0; ni < 4; ni++)
            bfr[ni] = *(const short8*)(wf2 + ni * 16 * 8);
#pragma unroll
        for (int mi = 0; mi < 4; mi++)
            af[mi] = *(const short8*)(hf + ((size_t)(kt * 4 + quad) * 128 + wrow * 64 + mi * 16 + lm) * 8);
#pragma unroll
        for (int mi = 0; mi < 4; mi++)
#pragma unroll
            for (int ni = 0; ni < 4; ni++)
                acc[mi][ni] = __builtin_amdgcn_mfma_f32_16x16x32_bf16(af[mi], bfr[ni], acc[mi][ni], 0, 0, 0);
    }

    float bcol[4];
#pragma unroll
    for (int ni = 0; ni < 4; ni++) bcol[ni] = b_blk[wcol * 64 + ni * 16 + lm];
    float s_c[4] = {0.f, 0.f, 0.f, 0.f}, ss_c[4] = {0.f, 0.f, 0.f, 0.f};
#pragma unroll
    for (int mi = 0; mi < 4; mi++)
#pragma unroll
        for (int r = 0; r < 4; r++)
#pragma unroll
            for (int ni = 0; ni < 4; ni++) {
                const float zv = acc[mi][ni][r] + bcol[ni];
                s_c[ni] += zv;
                ss_c[ni] += zv * zv;
            }
#pragma unroll
    for (int ni = 0; ni < 4; ni++) {
        float s = s_c[ni], ss = ss_c[ni];
        s  += __shfl_xor(s, 16);  s  += __shfl_xor(s, 32);
        ss += __shfl_xor(ss, 16); ss += __shfl_xor(ss, 32);
        if (quad == 0) {
            atomicAdd(&csum_s[wcol * 64 + ni * 16 + lm], s);
            atomicAdd(&csumsq_s[wcol * 64 + ni * 16 + lm], ss);
        }
    }
    __syncthreads();
    if (tid < 128) {
        sumP[(size_t)blockIdx.x * 128 + tid] = csum_s[tid];
        sumsqP[(size_t)blockIdx.x * 128 + tid] = csumsq_s[tid];
    }
}

// ---------------- BN finalize ----------------------------------------------
__global__ __launch_bounds__(256) void k_bnfin(
    const float* __restrict__ sumP, const float* __restrict__ sumsqP,
    const float* __restrict__ gamma, const float* __restrict__ beta,
    float* __restrict__ scale, float* __restrict__ shift)
{
    const int c = blockIdx.x;
    const int tid = threadIdx.x;
    float s = 0.f, ss = 0.f;
    for (int i = tid; i < 1024; i += 256) {
        s  += sumP[(size_t)i * 128 + c];
        ss += sumsqP[(size_t)i * 128 + c];
    }
#pragma unroll
    for (int off = 32; off; off >>= 1) {
        s  += __shfl_xor(s, off, 64);
        ss += __shfl_xor(ss, off, 64);
    }
    __shared__ float rs[4], rss[4];
    const int wid = tid >> 6, lane = tid & 63;
    if (lane == 0) { rs[wid] = s; rss[wid] = ss; }
    __syncthreads();
    if (tid == 0) {
        const float S  = rs[0] + rs[1] + rs[2] + rs[3];
        const float SS = rss[0] + rss[1] + rss[2] + rss[3];
        const float inv_m = 1.0f / (float)MB_;
        const float mu = S * inv_m;
        const float var = SS * inv_m - mu * mu;
        const float sc = gamma[c] * rsqrtf(var + 1e-5f);
        scale[c] = sc;
        shift[c] = beta[c] - mu * sc;
    }
}

// ---------------- Phase C: recompute z, BN, residual, logits, t -------------
// grid 1024 (128 rows), block 256. h staged frag-major LDS (coalesced).
__global__ __launch_bounds__(256, 3) void k_phaseC(
    const unsigned short* __restrict__ h_f, const unsigned short* __restrict__ Wblk_f,
    const float* __restrict__ b_blk,
    const float* __restrict__ scale, const float* __restrict__ shift,
    const float* __restrict__ W_fc, const float* __restrict__ b_fc,
    const float* __restrict__ mask, const float* __restrict__ gumbel,
    float* __restrict__ t_bho)
{
    __shared__ __align__(16) unsigned short hb_f[16384];  // frag-major tile
    __shared__ float wfc_s[128 * 8];
    __shared__ float sc_s[128], sh_s[128];

    const int tid = threadIdx.x;
    const int R0 = blockIdx.x * 128;
    const int wave = tid >> 6;
    const int wrow = wave >> 1, wcol = wave & 1;
    const int lane = tid & 63;
    const int lm = lane & 15, quad = lane >> 4;

    for (int i = tid; i < 1024; i += 256) wfc_s[i] = W_fc[i];
    if (tid < 128) { sc_s[tid] = scale[tid]; sh_s[tid] = shift[tid]; }
    const unsigned short* hf = h_f + (size_t)blockIdx.x * 16384;
#pragma unroll
    for (int i = 0; i < 8; i++) {
        const int idx = i * 256 + tid;
        const short8 v = *(const short8*)(hf + (size_t)idx * 8);
        *(short8*)(&hb_f[idx * 8]) = v;
    }
    __syncthreads();

    f32x4 acc[4][4];
#pragma unroll
    for (int i = 0; i < 4; i++)
#pragma unroll
        for (int j = 0; j < 4; j++) acc[i][j] = (f32x4){0.f, 0.f, 0.f, 0.f};
#pragma unroll
    for (int kt = 0; kt < 4; kt++) {
        short8 af[4], bfr[4];
        const unsigned short* wf2 = Wblk_f + ((size_t)(kt * 4 + quad) * 128 + wcol * 64 + lm) * 8;
#pragma unroll
        for (int ni = 0; ni < 4; ni++)
            bfr[ni] = *(const short8*)(wf2 + ni * 16 * 8);
#pragma unroll
        for (int mi = 0; mi < 4; mi++)
            af[mi] = *(const short8*)(&hb_f[((kt * 4 + quad) * 128 + wrow * 64 + mi * 16 + lm) * 8]);
#pragma unroll
        for (int mi = 0; mi < 4; mi++)
#pragma unroll
            for (int ni = 0; ni < 4; ni++)
                acc[mi][ni] = __builtin_amdgcn_mfma_f32_16x16x32_bf16(af[mi], bfr[ni], acc[mi][ni], 0, 0, 0);
    }
    __syncthreads();   // all A-frag reads done before in-place update

    // epilogue: hb = relu(z*sc+sh) + h, in place (frag-major indexing)
    {
        float bcol[4];
#pragma unroll
        for (int ni = 0; ni < 4; ni++) bcol[ni] = b_blk[wcol * 64 + ni * 16 + lm];
#pragma unroll
        for (int mi = 0; mi < 4; mi++)
#pragma unroll
            for (int r = 0; r < 4; r++) {
                const int row = wrow * 64 + mi * 16 + quad * 4 + r;
#pragma unroll
                for (int ni = 0; ni < 4; ni++) {
                    const int col = wcol * 64 + ni * 16 + lm;
                    const int a = ((col >> 3) * 128 + row) * 8 + (col & 7);
                    const float zv = acc[mi][ni][r] + bcol[ni];
                    const float hv = bf2f(hb_f[a]);
                    hb_f[a] = f2bf(fmaxf(zv * sc_s[col] + sh_s[col], 0.f) + hv);
                }
            }
    }
    __syncthreads();

    // logits + gumbel: thread pair (row = tid>>1) splits K=128 in half
    {
        const int row = tid >> 1, half = tid & 1;
        const int grow = R0 + row;
        float a8[8];
#pragma unroll
        for (int j = 0; j < 8; j++) a8[j] = 0.f;
#pragma unroll 2
        for (int c8 = 0; c8 < 8; c8++) {
            const int c = half * 8 + c8;
            const short8 hv8 = *(const short8*)(&hb_f[(c * 128 + row) * 8]);
#pragma unroll
            for (int e = 0; e < 8; e++) {
                const float hv = bf2f((unsigned short)hv8[e]);
                const int k = c * 8 + e;
#pragma unroll
                for (int j = 0; j < 8; j++) a8[j] += hv * wfc_s[k * 8 + j];
            }
        }
#pragma unroll
        for (int j = 0; j < 8; j++) a8[j] += __shfl_xor(a8[j], 1);
        const float mk = mask[grow];
        const int b = grow >> 12, o = grow & 4095;
#pragma unroll
        for (int jj = 0; jj < 4; jj++) {
            const int j = half * 4 + jj;
            const float t = (a8[j] + b_fc[j]) * mk + gumbel[(size_t)grow * 8 + j];
            t_bho[((size_t)(b * 8 + j)) * O_ + o] = t;
        }
    }
}

// ---------------- softmax over O per (b,h), coalesced -----------------------
__global__ __launch_bounds__(256) void k_softmax(
    const float* __restrict__ t_in, float* __restrict__ w_out)
{
    const int bh = blockIdx.x;
    const int tid = threadIdx.x;
    const float* tp = t_in + (size_t)bh * O_;
    float4 v[4];
    float mx = -3.4e38f;
#pragma unroll
    for (int it = 0; it < 4; it++) {
        v[it] = *(const float4*)(tp + it * 1024 + tid * 4);
        mx = fmaxf(mx, fmaxf(fmaxf(v[it].x, v[it].y), fmaxf(v[it].z, v[it].w)));
    }
#pragma unroll
    for (int off = 32; off; off >>= 1) mx = fmaxf(mx, __shfl_xor(mx, off, 64));
    __shared__ float rm[4], rsum[4];
    const int wid = tid >> 6, lane = tid & 63;
    if (lane == 0) rm[wid] = mx;
    __syncthreads();
    mx = fmaxf(fmaxf(rm[0], rm[1]), fmaxf(rm[2], rm[3]));
    float sum = 0.f;
#pragma unroll
    for (int it = 0; it < 4; it++) {
        v[it].x = __expf(v[it].x - mx); v[it].y = __expf(v[it].y - mx);
        v[it].z = __expf(v[it].z - mx); v[it].w = __expf(v[it].w - mx);
        sum += v[it].x + v[it].y + v[it].z + v[it].w;
    }
#pragma unroll
    for (int off = 32; off; off >>= 1) sum += __shfl_xor(sum, off, 64);
    if (lane == 0) rsum[wid] = sum;
    __syncthreads();
    sum = rsum[0] + rsum[1] + rsum[2] + rsum[3];
    const float inv = 1.f / sum;
    float* wp = w_out + (size_t)bh * O_;
#pragma unroll
    for (int it = 0; it < 4; it++) {
        float4 o;
        o.x = v[it].x * inv; o.y = v[it].y * inv; o.z = v[it].z * inv; o.w = v[it].w * inv;
        *(float4*)(wp + it * 1024 + tid * 4) = o;
    }
}

// ---------------- pooled partials -------------------------------------------
__global__ __launch_bounds__(256) void k_pool(
    const float* __restrict__ x, const float* __restrict__ w_in,
    float* __restrict__ pp)
{
    __shared__ float ws_s[8][128];
    const int tid = threadIdx.x;
    const int oc = blockIdx.x;
    const int b = blockIdx.y;
    const int wave = tid >> 6, lane = tid & 63;
    const int f = wave * 64 + lane;
    for (int i = tid; i < 1024; i += 256) {
        const int hh = i >> 7, oi = i & 127;
        ws_s[hh][oi] = w_in[((size_t)(b * 8 + hh)) * O_ + oc * 128 + oi];
    }
    __syncthreads();
    float acc[8];
#pragma unroll
    for (int hh = 0; hh < 8; hh++) acc[hh] = 0.f;
    const float* xp = x + ((size_t)(b * O_ + oc * 128)) * F_ + f;
#pragma unroll 1
    for (int oi = 0; oi < 128; oi += 4) {
        float xv[4];
#pragma unroll
        for (int u = 0; u < 4; u++) xv[u] = xp[(size_t)(oi + u) * F_];
#pragma unroll
        for (int u = 0; u < 4; u++)
#pragma unroll
            for (int hh = 0; hh < 8; hh++) acc[hh] += ws_s[hh][oi + u] * xv[u];
    }
    float* outp = pp + ((size_t)(oc * 32 + b)) * 2048;
#pragma unroll
    for (int hh = 0; hh < 8; hh++) outp[hh * 256 + f] = acc[hh];
}

// ---------------- reduce pooled partials ------------------------------------
__global__ __launch_bounds__(256) void k_reduce_pool(
    const float* __restrict__ pp, float* __restrict__ out)
{
    const size_t i = (size_t)blockIdx.x * 256 + threadIdx.x;
    float s = 0.f;
#pragma unroll
    for (int oc = 0; oc < 32; oc++) s += pp[(size_t)oc * 65536 + i];
    out[i] = s;
}

extern "C" void kernel_launch(void* const* d_in, const int* in_sizes, int n_in,
                              void* d_out, int out_size, void* d_ws, size_t ws_size,
                              hipStream_t stream)
{
    const float* x      = (const float*)d_in[0];
    const float* gumbel = (const float*)d_in[1];
    const float* W_in   = (const float*)d_in[2];
    const float* b_in   = (const float*)d_in[3];
    const float* W_blk  = (const float*)d_in[4];
    const float* b_blk  = (const float*)d_in[5];
    const float* gamma  = (const float*)d_in[6];
    const float* beta   = (const float*)d_in[7];
    const float* W_fc   = (const float*)d_in[8];
    const float* b_fc   = (const float*)d_in[9];
    float* out = (float*)d_out;
    char* ws = (char*)d_ws;

    unsigned short* h_f   = (unsigned short*)(ws + 0);             // 33554432
    float* mask   = (float*)(ws + 33554432);                        // 524288
    float* sumP   = (float*)(ws + 34078720);                        // 524288
    float* sumsqP = (float*)(ws + 34603008);                        // 524288
    float* scale  = (float*)(ws + 35127296);                        // 512
    float* shift  = (float*)(ws + 35127808);                        // 512
    float* t_buf  = (float*)(ws + 35128320);                        // 4194304
    float* w_buf  = (float*)(ws + 39322624);                        // 4194304
    float* pp     = (float*)(ws + 43516928);                        // 8388608
    unsigned short* Win_f  = (unsigned short*)(ws + 51905536);      // 65536
    unsigned short* Wblk_f = (unsigned short*)(ws + 51971072);      // 32768

    k_prep<<<192, 256, 0, stream>>>(W_in, W_blk, Win_f, Wblk_f);
    k_gemm1<<<1024, 256, 0, stream>>>(x, Win_f, b_in, h_f, mask);
    k_gemm2stats<<<1024, 256, 0, stream>>>(h_f, Wblk_f, b_blk, sumP, sumsqP);
    k_bnfin<<<128, 256, 0, stream>>>(sumP, sumsqP, gamma, beta, scale, shift);
    k_phaseC<<<1024, 256, 0, stream>>>(h_f, Wblk_f, b_blk, scale, shift, W_fc, b_fc, mask, gumbel, t_buf);
    k_softmax<<<256, 256, 0, stream>>>(t_buf, w_buf);
    k_pool<<<dim3(32, 32), 256, 0, stream>>>(x, w_buf, pp);
    k_reduce_pool<<<256, 256, 0, stream>>>(pp, out);
}

// Round 7
// 304.096 us; speedup vs baseline: 1.0898x; 1.0402x over previous
//
#include <hip/hip_runtime.h>
#include <hip/hip_bf16.h>
#include <math.h>

// Problem constants: B=32, O=4096, F=256, H=8, HID=128
#define MB_ 131072
#define F_  256
#define HID_ 128
#define H_  8
#define O_  4096
#define B_  32

typedef __attribute__((ext_vector_type(8))) short short8;
typedef __attribute__((ext_vector_type(4))) float f32x4;

static __device__ __forceinline__ unsigned short f2bf(float f) {
    unsigned int u = __float_as_uint(f);
    unsigned int r = (u + 0x7fffu + ((u >> 16) & 1u)) >> 16;  // RNE
    return (unsigned short)r;
}
static __device__ __forceinline__ float bf2f(unsigned short u) {
    return __uint_as_float(((unsigned int)u) << 16);
}

// ---------------- Prep: weights -> fragment-major bf16 ----------------------
// W_f[(c*128 + n)*8 + j] = W[k = c*8 + j][n]; B-frag = 16 B contiguous/lane.
__global__ __launch_bounds__(256) void k_prep(
    const float* __restrict__ W_in, const float* __restrict__ W_blk,
    unsigned short* __restrict__ Win_f, unsigned short* __restrict__ Wblk_f)
{
    const int idx = blockIdx.x * 256 + threadIdx.x;
    if (idx < 32768) {                        // Win_f: c 0..31 (K=256)
        const int j = idx & 7, n = (idx >> 3) & 127, c = idx >> 10;
        Win_f[idx] = f2bf(W_in[(size_t)(c * 8 + j) * HID_ + n]);
    } else if (idx < 49152) {                 // Wblk_f: c 0..15 (K=128)
        const int i2 = idx - 32768;
        const int j = i2 & 7, n = (i2 >> 3) & 127, c = i2 >> 10;
        Wblk_f[i2] = f2bf(W_blk[(size_t)(c * 8 + j) * HID_ + n]);
    }
}

// ---------------- Precast: x fp32 -> bf16 row-major, + row mask -------------
// Fully sequential streaming: one wave per row (1 KB read, 512 B write).
// grid 2048 blocks; block covers 64 consecutive rows.
__global__ __launch_bounds__(256) void k_precast(
    const float* __restrict__ x, unsigned short* __restrict__ xb,
    float* __restrict__ mask_out)
{
    const int tid = threadIdx.x, wv = tid >> 6, ln = tid & 63;
    const int rbase = blockIdx.x * 64;
#pragma unroll 2
    for (int it = 0; it < 16; it++) {
        const int row = rbase + it * 4 + wv;
        const float4 v = *(const float4*)(x + (size_t)row * F_ + ln * 4);
        float ss = v.x * v.x + v.y * v.y + v.z * v.z + v.w * v.w;
        ushort4 o;
        o.x = f2bf(v.x); o.y = f2bf(v.y); o.z = f2bf(v.z); o.w = f2bf(v.w);
        *(ushort4*)(xb + (size_t)row * F_ + ln * 4) = o;
#pragma unroll
        for (int off = 32; off; off >>= 1) ss += __shfl_xor(ss, off, 64);
        if (ln == 0) mask_out[row] = (ss != 0.f) ? 1.f : 0.f;
    }
}

// ---------------- GEMM1 fused: h=relu(x@W_in+b), h_f store, BN stats of z ---
// grid 1024, block 256 (4 waves), 2 blocks/CU (64 KB LDS).
// x tile staged as ONE contiguous 64 KB stream (bf16), XOR-swizzled 16 B
// chunks for conflict-free MFMA A-frag reads. Zero barriers in K-loops.
// Weights direct from global in frag-major layout (L2-hot). GEMM2 (BN stats)
// reuses the h tile in LDS; z never materialized.
__global__ __launch_bounds__(256, 2) void k_gemm1f(
    const unsigned short* __restrict__ xb, const unsigned short* __restrict__ Win_f,
    const unsigned short* __restrict__ Wblk_f,
    const float* __restrict__ b_in, const float* __restrict__ b_blk,
    unsigned short* __restrict__ h_f,
    float* __restrict__ sumP, float* __restrict__ sumsqP)
{
    __shared__ __align__(16) unsigned short x_s[128 * 256];  // 64 KB, swizzled
    __shared__ float csum_s[128], csumsq_s[128];
    unsigned short* hb_s = x_s;   // h tile (128x136 row-major) reuses x_s

    const int tid = threadIdx.x;
    const int R0 = blockIdx.x * 128;
    const int wave = tid >> 6;
    const int wrow = wave >> 1, wcol = wave & 1;
    const int lane = tid & 63;
    const int lm = lane & 15, quad = lane >> 4;

    if (tid < 128) { csum_s[tid] = 0.f; csumsq_s[tid] = 0.f; }

    // ---- stage x tile: contiguous 64 KB read, swizzled LDS scatter ----
    {
        const unsigned short* src = xb + (size_t)R0 * F_;
#pragma unroll
        for (int i = 0; i < 16; i++) {
            const int idx = i * 256 + tid;
            const int row = idx >> 5, c = idx & 31;       // 32 chunks of 16 B/row
            const int pc = c ^ (row & 7);                 // bank de-conflict
            const short8 v = *(const short8*)(src + (size_t)idx * 8);
            *(short8*)(&x_s[(row * 32 + pc) * 8]) = v;
        }
    }
    __syncthreads();

    f32x4 acc[4][4];
#pragma unroll
    for (int i = 0; i < 4; i++)
#pragma unroll
        for (int j = 0; j < 4; j++) acc[i][j] = (f32x4){0.f, 0.f, 0.f, 0.f};

    // ---- GEMM1: K=256 in 8 kt, pure LDS + L2, no barriers ----
    for (int kt = 0; kt < 8; kt++) {
        short8 af[4], bfr[4];
        const unsigned short* wf = Win_f + ((size_t)(kt * 4 + quad) * 128 + wcol * 64 + lm) * 8;
#pragma unroll
        for (int ni = 0; ni < 4; ni++)
            bfr[ni] = *(const short8*)(wf + ni * 16 * 8);
        const int cidx = kt * 4 + quad;
#pragma unroll
        for (int mi = 0; mi < 4; mi++) {
            const int row = wrow * 64 + mi * 16 + lm;
            const int pc = cidx ^ (row & 7);
            af[mi] = *(const short8*)(&x_s[(row * 32 + pc) * 8]);
        }
#pragma unroll
        for (int mi = 0; mi < 4; mi++)
#pragma unroll
            for (int ni = 0; ni < 4; ni++)
                acc[mi][ni] = __builtin_amdgcn_mfma_f32_16x16x32_bf16(af[mi], bfr[ni], acc[mi][ni], 0, 0, 0);
    }
    __syncthreads();   // all x_s reads done; region becomes hb_s

    // ---- epilogue 1: bias + relu -> hb_s (row-major, 136 stride) ----
    {
        float bcol[4];
#pragma unroll
        for (int ni = 0; ni < 4; ni++) bcol[ni] = b_in[wcol * 64 + ni * 16 + lm];
#pragma unroll
        for (int mi = 0; mi < 4; mi++)
#pragma unroll
            for (int r = 0; r < 4; r++) {
                const int row = wrow * 64 + mi * 16 + quad * 4 + r;
#pragma unroll
                for (int ni = 0; ni < 4; ni++) {
                    const int col = wcol * 64 + ni * 16 + lm;
                    hb_s[row * 136 + col] = f2bf(fmaxf(acc[mi][ni][r] + bcol[ni], 0.f));
                }
            }
    }
    __syncthreads();

    // ---- h_f store: frag-major, contiguous 4 KB per instruction ----
    {
        unsigned short* hf = h_f + (size_t)blockIdx.x * 16384;
#pragma unroll
        for (int i = 0; i < 8; i++) {
            const int idx = i * 256 + tid;            // (c,row) chunk id
            const int c = idx >> 7, row = idx & 127;
            const short8 v = *(const short8*)(&hb_s[row * 136 + c * 8]);
            *(short8*)(hf + (size_t)idx * 8) = v;
        }
    }

    // ---- GEMM2: z = h @ W_blk (A from hb_s, B frag-major L2) ----
#pragma unroll
    for (int i = 0; i < 4; i++)
#pragma unroll
        for (int j = 0; j < 4; j++) acc[i][j] = (f32x4){0.f, 0.f, 0.f, 0.f};
#pragma unroll
    for (int kt = 0; kt < 4; kt++) {
        short8 af[4], bfr[4];
        const unsigned short* wf2 = Wblk_f + ((size_t)(kt * 4 + quad) * 128 + wcol * 64 + lm) * 8;
#pragma unroll
        for (int ni = 0; ni < 4; ni++)
            bfr[ni] = *(const short8*)(wf2 + ni * 16 * 8);
#pragma unroll
        for (int mi = 0; mi < 4; mi++)
            af[mi] = *(const short8*)(&hb_s[(wrow * 64 + mi * 16 + lm) * 136 + kt * 32 + quad * 8]);
#pragma unroll
        for (int mi = 0; mi < 4; mi++)
#pragma unroll
            for (int ni = 0; ni < 4; ni++)
                acc[mi][ni] = __builtin_amdgcn_mfma_f32_16x16x32_bf16(af[mi], bfr[ni], acc[mi][ni], 0, 0, 0);
    }

    // ---- epilogue 2: BN partial sums (z not stored) ----
    {
        float bcol[4];
#pragma unroll
        for (int ni = 0; ni < 4; ni++) bcol[ni] = b_blk[wcol * 64 + ni * 16 + lm];
        float s_c[4] = {0.f, 0.f, 0.f, 0.f}, ss_c[4] = {0.f, 0.f, 0.f, 0.f};
#pragma unroll
        for (int mi = 0; mi < 4; mi++)
#pragma unroll
            for (int r = 0; r < 4; r++)
#pragma unroll
                for (int ni = 0; ni < 4; ni++) {
                    const float zv = acc[mi][ni][r] + bcol[ni];
                    s_c[ni] += zv;
                    ss_c[ni] += zv * zv;
                }
#pragma unroll
        for (int ni = 0; ni < 4; ni++) {
            float s = s_c[ni], ss = ss_c[ni];
            s  += __shfl_xor(s, 16);  s  += __shfl_xor(s, 32);
            ss += __shfl_xor(ss, 16); ss += __shfl_xor(ss, 32);
            if (quad == 0) {
                atomicAdd(&csum_s[wcol * 64 + ni * 16 + lm], s);
                atomicAdd(&csumsq_s[wcol * 64 + ni * 16 + lm], ss);
            }
        }
    }
    __syncthreads();
    if (tid < 128) {
        sumP[(size_t)blockIdx.x * 128 + tid] = csum_s[tid];
        sumsqP[(size_t)blockIdx.x * 128 + tid] = csumsq_s[tid];
    }
}

// ---------------- BN finalize ----------------------------------------------
__global__ __launch_bounds__(256) void k_bnfin(
    const float* __restrict__ sumP, const float* __restrict__ sumsqP,
    const float* __restrict__ gamma, const float* __restrict__ beta,
    float* __restrict__ scale, float* __restrict__ shift)
{
    const int c = blockIdx.x;
    const int tid = threadIdx.x;
    float s = 0.f, ss = 0.f;
    for (int i = tid; i < 1024; i += 256) {
        s  += sumP[(size_t)i * 128 + c];
        ss += sumsqP[(size_t)i * 128 + c];
    }
#pragma unroll
    for (int off = 32; off; off >>= 1) {
        s  += __shfl_xor(s, off, 64);
        ss += __shfl_xor(ss, off, 64);
    }
    __shared__ float rs[4], rss[4];
    const int wid = tid >> 6, lane = tid & 63;
    if (lane == 0) { rs[wid] = s; rss[wid] = ss; }
    __syncthreads();
    if (tid == 0) {
        const float S  = rs[0] + rs[1] + rs[2] + rs[3];
        const float SS = rss[0] + rss[1] + rss[2] + rss[3];
        const float inv_m = 1.0f / (float)MB_;
        const float mu = S * inv_m;
        const float var = SS * inv_m - mu * mu;
        const float sc = gamma[c] * rsqrtf(var + 1e-5f);
        scale[c] = sc;
        shift[c] = beta[c] - mu * sc;
    }
}

// ---------------- Phase C: recompute z, BN, residual, logits, t -------------
// grid 1024 (128 rows), block 256. h staged frag-major LDS (coalesced).
__global__ __launch_bounds__(256, 3) void k_phaseC(
    const unsigned short* __restrict__ h_f, const unsigned short* __restrict__ Wblk_f,
    const float* __restrict__ b_blk,
    const float* __restrict__ scale, const float* __restrict__ shift,
    const float* __restrict__ W_fc, const float* __restrict__ b_fc,
    const float* __restrict__ mask, const float* __restrict__ gumbel,
    float* __restrict__ t_bho)
{
    __shared__ __align__(16) unsigned short hb_f[16384];  // frag-major tile
    __shared__ float wfc_s[128 * 8];
    __shared__ float sc_s[128], sh_s[128];

    const int tid = threadIdx.x;
    const int R0 = blockIdx.x * 128;
    const int wave = tid >> 6;
    const int wrow = wave >> 1, wcol = wave & 1;
    const int lane = tid & 63;
    const int lm = lane & 15, quad = lane >> 4;

    for (int i = tid; i < 1024; i += 256) wfc_s[i] = W_fc[i];
    if (tid < 128) { sc_s[tid] = scale[tid]; sh_s[tid] = shift[tid]; }
    const unsigned short* hf = h_f + (size_t)blockIdx.x * 16384;
#pragma unroll
    for (int i = 0; i < 8; i++) {
        const int idx = i * 256 + tid;
        const short8 v = *(const short8*)(hf + (size_t)idx * 8);
        *(short8*)(&hb_f[idx * 8]) = v;
    }
    __syncthreads();

    f32x4 acc[4][4];
#pragma unroll
    for (int i = 0; i < 4; i++)
#pragma unroll
        for (int j = 0; j < 4; j++) acc[i][j] = (f32x4){0.f, 0.f, 0.f, 0.f};
#pragma unroll
    for (int kt = 0; kt < 4; kt++) {
        short8 af[4], bfr[4];
        const unsigned short* wf2 = Wblk_f + ((size_t)(kt * 4 + quad) * 128 + wcol * 64 + lm) * 8;
#pragma unroll
        for (int ni = 0; ni < 4; ni++)
            bfr[ni] = *(const short8*)(wf2 + ni * 16 * 8);
#pragma unroll
        for (int mi = 0; mi < 4; mi++)
            af[mi] = *(const short8*)(&hb_f[((kt * 4 + quad) * 128 + wrow * 64 + mi * 16 + lm) * 8]);
#pragma unroll
        for (int mi = 0; mi < 4; mi++)
#pragma unroll
            for (int ni = 0; ni < 4; ni++)
                acc[mi][ni] = __builtin_amdgcn_mfma_f32_16x16x32_bf16(af[mi], bfr[ni], acc[mi][ni], 0, 0, 0);
    }
    __syncthreads();   // all A-frag reads done before in-place update

    // epilogue: hb = relu(z*sc+sh) + h, in place (frag-major indexing)
    {
        float bcol[4];
#pragma unroll
        for (int ni = 0; ni < 4; ni++) bcol[ni] = b_blk[wcol * 64 + ni * 16 + lm];
#pragma unroll
        for (int mi = 0; mi < 4; mi++)
#pragma unroll
            for (int r = 0; r < 4; r++) {
                const int row = wrow * 64 + mi * 16 + quad * 4 + r;
#pragma unroll
                for (int ni = 0; ni < 4; ni++) {
                    const int col = wcol * 64 + ni * 16 + lm;
                    const int a = ((col >> 3) * 128 + row) * 8 + (col & 7);
                    const float zv = acc[mi][ni][r] + bcol[ni];
                    const float hv = bf2f(hb_f[a]);
                    hb_f[a] = f2bf(fmaxf(zv * sc_s[col] + sh_s[col], 0.f) + hv);
                }
            }
    }
    __syncthreads();

    // logits + gumbel: thread pair (row = tid>>1) splits K=128 in half
    {
        const int row = tid >> 1, half = tid & 1;
        const int grow = R0 + row;
        float a8[8];
#pragma unroll
        for (int j = 0; j < 8; j++) a8[j] = 0.f;
#pragma unroll 2
        for (int c8 = 0; c8 < 8; c8++) {
            const int c = half * 8 + c8;
            const short8 hv8 = *(const short8*)(&hb_f[(c * 128 + row) * 8]);
#pragma unroll
            for (int e = 0; e < 8; e++) {
                const float hv = bf2f((unsigned short)hv8[e]);
                const int k = c * 8 + e;
#pragma unroll
                for (int j = 0; j < 8; j++) a8[j] += hv * wfc_s[k * 8 + j];
            }
        }
#pragma unroll
        for (int j = 0; j < 8; j++) a8[j] += __shfl_xor(a8[j], 1);
        const float mk = mask[grow];
        const int b = grow >> 12, o = grow & 4095;
#pragma unroll
        for (int jj = 0; jj < 4; jj++) {
            const int j = half * 4 + jj;
            const float t = (a8[j] + b_fc[j]) * mk + gumbel[(size_t)grow * 8 + j];
            t_bho[((size_t)(b * 8 + j)) * O_ + o] = t;
        }
    }
}

// ---------------- softmax over O per (b,h), coalesced -----------------------
__global__ __launch_bounds__(256) void k_softmax(
    const float* __restrict__ t_in, float* __restrict__ w_out)
{
    const int bh = blockIdx.x;
    const int tid = threadIdx.x;
    const float* tp = t_in + (size_t)bh * O_;
    float4 v[4];
    float mx = -3.4e38f;
#pragma unroll
    for (int it = 0; it < 4; it++) {
        v[it] = *(const float4*)(tp + it * 1024 + tid * 4);
        mx = fmaxf(mx, fmaxf(fmaxf(v[it].x, v[it].y), fmaxf(v[it].z, v[it].w)));
    }
#pragma unroll
    for (int off = 32; off; off >>= 1) mx = fmaxf(mx, __shfl_xor(mx, off, 64));
    __shared__ float rm[4], rsum[4];
    const int wid = tid >> 6, lane = tid & 63;
    if (lane == 0) rm[wid] = mx;
    __syncthreads();
    mx = fmaxf(fmaxf(rm[0], rm[1]), fmaxf(rm[2], rm[3]));
    float sum = 0.f;
#pragma unroll
    for (int it = 0; it < 4; it++) {
        v[it].x = __expf(v[it].x - mx); v[it].y = __expf(v[it].y - mx);
        v[it].z = __expf(v[it].z - mx); v[it].w = __expf(v[it].w - mx);
        sum += v[it].x + v[it].y + v[it].z + v[it].w;
    }
#pragma unroll
    for (int off = 32; off; off >>= 1) sum += __shfl_xor(sum, off, 64);
    if (lane == 0) rsum[wid] = sum;
    __syncthreads();
    sum = rsum[0] + rsum[1] + rsum[2] + rsum[3];
    const float inv = 1.f / sum;
    float* wp = w_out + (size_t)bh * O_;
#pragma unroll
    for (int it = 0; it < 4; it++) {
        float4 o;
        o.x = v[it].x * inv; o.y = v[it].y * inv; o.z = v[it].z * inv; o.w = v[it].w * inv;
        *(float4*)(wp + it * 1024 + tid * 4) = o;
    }
}

// ---------------- pooled partials (reads bf16 x) ----------------------------
__global__ __launch_bounds__(256) void k_pool(
    const unsigned short* __restrict__ xb, const float* __restrict__ w_in,
    float* __restrict__ pp)
{
    __shared__ float ws_s[8][128];
    const int tid = threadIdx.x;
    const int oc = blockIdx.x;
    const int b = blockIdx.y;
    const int wave = tid >> 6, lane = tid & 63;
    const int f = wave * 64 + lane;
    for (int i = tid; i < 1024; i += 256) {
        const int hh = i >> 7, oi = i & 127;
        ws_s[hh][oi] = w_in[((size_t)(b * 8 + hh)) * O_ + oc * 128 + oi];
    }
    __syncthreads();
    float acc[8];
#pragma unroll
    for (int hh = 0; hh < 8; hh++) acc[hh] = 0.f;
    const unsigned short* xp = xb + ((size_t)(b * O_ + oc * 128)) * F_ + f;
#pragma unroll 1
    for (int oi = 0; oi < 128; oi += 4) {
        float xv[4];
#pragma unroll
        for (int u = 0; u < 4; u++) xv[u] = bf2f(xp[(size_t)(oi + u) * F_]);
#pragma unroll
        for (int u = 0; u < 4; u++)
#pragma unroll
            for (int hh = 0; hh < 8; hh++) acc[hh] += ws_s[hh][oi + u] * xv[u];
    }
    float* outp = pp + ((size_t)(oc * 32 + b)) * 2048;
#pragma unroll
    for (int hh = 0; hh < 8; hh++) outp[hh * 256 + f] = acc[hh];
}

// ---------------- reduce pooled partials ------------------------------------
__global__ __launch_bounds__(256) void k_reduce_pool(
    const float* __restrict__ pp, float* __restrict__ out)
{
    const size_t i = (size_t)blockIdx.x * 256 + threadIdx.x;
    float s = 0.f;
#pragma unroll
    for (int oc = 0; oc < 32; oc++) s += pp[(size_t)oc * 65536 + i];
    out[i] = s;
}

extern "C" void kernel_launch(void* const* d_in, const int* in_sizes, int n_in,
                              void* d_out, int out_size, void* d_ws, size_t ws_size,
                              hipStream_t stream)
{
    const float* x      = (const float*)d_in[0];
    const float* gumbel = (const float*)d_in[1];
    const float* W_in   = (const float*)d_in[2];
    const float* b_in   = (const float*)d_in[3];
    const float* W_blk  = (const float*)d_in[4];
    const float* b_blk  = (const float*)d_in[5];
    const float* gamma  = (const float*)d_in[6];
    const float* beta   = (const float*)d_in[7];
    const float* W_fc   = (const float*)d_in[8];
    const float* b_fc   = (const float*)d_in[9];
    float* out = (float*)d_out;
    char* ws = (char*)d_ws;

    unsigned short* xb    = (unsigned short*)(ws + 0);             // 67108864
    unsigned short* h_f   = (unsigned short*)(ws + 67108864);      // 33554432
    float* mask   = (float*)(ws + 100663296);                       // 524288
    float* sumP   = (float*)(ws + 101187584);                       // 524288
    float* sumsqP = (float*)(ws + 101711872);                       // 524288
    float* scale  = (float*)(ws + 102236160);                       // 512
    float* shift  = (float*)(ws + 102236672);                       // 512
    float* t_buf  = (float*)(ws + 102237184);                       // 4194304
    float* w_buf  = (float*)(ws + 106431488);                       // 4194304
    float* pp     = (float*)(ws + 110625792);                       // 8388608
    unsigned short* Win_f  = (unsigned short*)(ws + 119014400);     // 65536
    unsigned short* Wblk_f = (unsigned short*)(ws + 119079936);     // 32768

    k_prep<<<192, 256, 0, stream>>>(W_in, W_blk, Win_f, Wblk_f);
    k_precast<<<2048, 256, 0, stream>>>(x, xb, mask);
    k_gemm1f<<<1024, 256, 0, stream>>>(xb, Win_f, Wblk_f, b_in, b_blk, h_f, sumP, sumsqP);
    k_bnfin<<<128, 256, 0, stream>>>(sumP, sumsqP, gamma, beta, scale, shift);
    k_phaseC<<<1024, 256, 0, stream>>>(h_f, Wblk_f, b_blk, scale, shift, W_fc, b_fc, mask, gumbel, t_buf);
    k_softmax<<<256, 256, 0, stream>>>(t_buf, w_buf);
    k_pool<<<dim3(32, 32), 256, 0, stream>>>(xb, w_buf, pp);
    k_reduce_pool<<<256, 256, 0, stream>>>(pp, out);
}